// Round 3
// baseline (238.787 us; speedup 1.0000x reference)
//
#include <hip/hip_runtime.h>

// out = (x @ R^T) @ codes^T + bias, where codes = codebook[indices]
// x: [32,4096] f32, indices: [8192,4096] i32(0..15), codebook:[16] f32,
// R: [4096,4096] f32, bias: [8192] f32, out: [32,8192] f32.
//
// K0: y_buf = 0 (static __device__ buffer)
// K1: out = bias (prologue) ; y_buf += x @ R^T   (bf16 MFMA, ksplit 8, 4 chunks, depth-2 pipeline)
// K2: out += y @ codes^T                         (bf16 MFMA, ksplit 4, 8 chunks, depth-2 pipeline)
//
// R9: (a) k2 ksplit 8->4: grid 512 = exactly 2 blocks/CU (kills the 256-block
// 1/3-occupancy tail), 8 chunks/block, atomics 2.1M->1.05M. (b) staging remap:
// each thread owns 8 contiguous cols -> 16B LDS writes; old 8B writes hit only
// even banks (2x conflict) at word-stride 68*r+2*c. New stride 68*r+4*c8 is a
// perfect 4-word rotation (8 words/bank = b128 minimum). (c) schedule rotated
// to "cvt c; issue loads c+2": loads fly 2 chunks ahead instead of 1.
//
// R8 post-mortem: the ~78us 512MB workspace poison fills are UNCONDITIONAL
// (untouched d_ws changed nothing). ~158us of dur_us is harness fixed cost;
// only the ~75us kernel slice is controllable.
//
// NOTE (R5 post-mortem): do NOT fuse K1/K2 with global-memory flags. The
// device-scope release/acquire fences required by cross-XCD non-coherence
// lower to L2 writeback/invalidate per block -> 750 us, HBM at 2% peak.

#define IN_F 4096
#define OUT_F 8192
#define BATCH 32
#define TSa 136   // LDS row stride in bf16 elems: 272 B = 68 words = 4-word bank rotation per row

typedef short bf16x8s __attribute__((ext_vector_type(8)));   // 8 bf16 in 4 VGPRs
typedef unsigned short u16x8 __attribute__((ext_vector_type(8)));
typedef float f32x4 __attribute__((ext_vector_type(4)));
typedef int   i32x4 __attribute__((ext_vector_type(4)));

// module-owned scratch: y = x @ R^T, [32][4096] f32 = 512 KB
__device__ float y_buf[BATCH * IN_F];

// fp32 -> bf16 bits, round-to-nearest-even
__device__ __forceinline__ unsigned short f2bf(float f) {
    union { float f; unsigned int u; } v; v.f = f;
    unsigned int u = v.u;
    return (unsigned short)((u + 0x7fffu + ((u >> 16) & 1u)) >> 16);
}

// ---- staging: tiles are [rows][128 cols]; thread t owns cols c8*8..c8*8+7
// (c8 = t&15) of rows rg, rg+16, ... (rg = t>>4). 32 B contiguous per row per
// thread on the global side; one 16 B LDS write per row on the LDS side. ----

// B tile: 64 rows -> 4 units/thread
__device__ __forceinline__ void loadB_nt(f32x4* dst, const float* base, int coff) {
    #pragma unroll
    for (int u = 0; u < 4; ++u) {
        dst[2*u]   = __builtin_nontemporal_load((const f32x4*)(base + (size_t)u * 16 * IN_F + coff));
        dst[2*u+1] = __builtin_nontemporal_load((const f32x4*)(base + (size_t)u * 16 * IN_F + coff + 4));
    }
}
__device__ __forceinline__ void loadBi_nt(i32x4* dst, const int* base, int coff) {
    #pragma unroll
    for (int u = 0; u < 4; ++u) {
        dst[2*u]   = __builtin_nontemporal_load((const i32x4*)(base + (size_t)u * 16 * IN_F + coff));
        dst[2*u+1] = __builtin_nontemporal_load((const i32x4*)(base + (size_t)u * 16 * IN_F + coff + 4));
    }
}
// A tile: 32 rows -> 2 units/thread
__device__ __forceinline__ void loadA(f32x4* dst, const float* base, int coff) {
    #pragma unroll
    for (int u = 0; u < 2; ++u) {
        dst[2*u]   = *(const f32x4*)(base + (size_t)u * 16 * IN_F + coff);
        dst[2*u+1] = *(const f32x4*)(base + (size_t)u * 16 * IN_F + coff + 4);
    }
}
__device__ __forceinline__ u16x8 pack8(const f32x4 a, const f32x4 b) {
    u16x8 pv;
    pv[0] = f2bf(a.x); pv[1] = f2bf(a.y); pv[2] = f2bf(a.z); pv[3] = f2bf(a.w);
    pv[4] = f2bf(b.x); pv[5] = f2bf(b.y); pv[6] = f2bf(b.z); pv[7] = f2bf(b.w);
    return pv;
}
__device__ __forceinline__ void cvtB16(unsigned short* lds, int lb, const f32x4* v) {
    #pragma unroll
    for (int u = 0; u < 4; ++u)
        *(u16x8*)&lds[lb + u * 16 * TSa] = pack8(v[2*u], v[2*u+1]);
}
__device__ __forceinline__ void cvtA16(unsigned short* lds, int lb, const f32x4* v) {
    #pragma unroll
    for (int u = 0; u < 2; ++u)
        *(u16x8*)&lds[lb + u * 16 * TSa] = pack8(v[2*u], v[2*u+1]);
}
__device__ __forceinline__ void cvtC16(unsigned short* lds, int lb, const i32x4* v,
                                       const unsigned int* cbp) {
    #pragma unroll
    for (int u = 0; u < 4; ++u) {
        const i32x4 a = v[2*u], b = v[2*u+1];
        uint4 pv;
        pv.x = cbp[(unsigned int)a.x | ((unsigned int)a.y << 4)];
        pv.y = cbp[(unsigned int)a.z | ((unsigned int)a.w << 4)];
        pv.z = cbp[(unsigned int)b.x | ((unsigned int)b.y << 4)];
        pv.w = cbp[(unsigned int)b.z | ((unsigned int)b.w << 4)];
        *(uint4*)&lds[lb + u * 16 * TSa] = pv;
    }
}
// 4 k-slices of 32 per chunk; acc0 = batch rows 0..15, acc1 = rows 16..31
__device__ __forceinline__ void mmstep(const unsigned short* B, const unsigned short* A,
                                       int bo, int ao, f32x4& acc0, f32x4& acc1) {
    #pragma unroll
    for (int ks = 0; ks < 4; ++ks) {
        bf16x8s bfr = *(const bf16x8s*)&B[bo + ks * 32];
        bf16x8s a0  = *(const bf16x8s*)&A[ao + ks * 32];
        bf16x8s a1  = *(const bf16x8s*)&A[ao + 16 * TSa + ks * 32];
        acc0 = __builtin_amdgcn_mfma_f32_16x16x32_bf16(a0, bfr, acc0, 0, 0, 0);
        acc1 = __builtin_amdgcn_mfma_f32_16x16x32_bf16(a1, bfr, acc1, 0, 0, 0);
    }
}

// ---------------- K0: zero the module-owned scratch ----------------
__global__ void __launch_bounds__(256) k0_zero() {
    int i = blockIdx.x * 256 + threadIdx.x;
    f32x4 z = {0.f, 0.f, 0.f, 0.f};
    ((f32x4*)y_buf)[i] = z;
}

// ---------------- K1: y = x @ R^T ----------------
// grid = 64 j-tiles * 8 k-splits = 512 blocks (2/CU), 4 chunks of 128 k
__global__ void __launch_bounds__(256, 3) k1_xRT(const float* __restrict__ x,
                                                 const float* __restrict__ R,
                                                 const float* __restrict__ bias,
                                                 float* __restrict__ out) {
    __shared__ unsigned short Bl[2][64 * TSa];  // R tile  [64 j][128 k] bf16
    __shared__ unsigned short Al[2][32 * TSa];  // x tile  [32 b][128 k] bf16

    const int tid  = threadIdx.x;
    const int jt   = blockIdx.x & 63;
    const int kq   = blockIdx.x >> 6;     // 0..7
    const int j0   = jt * 64;
    const int kb   = kq * 512;
    const int wave = tid >> 6, lane = tid & 63;
    const int n = lane & 15, quad = lane >> 4;
    const int rg = tid >> 4, c8 = tid & 15;

    const float* rbase = R + (size_t)(j0 + rg) * IN_F + kb + c8 * 8;
    const float* xbase = x + (size_t)rg * IN_F + kb + c8 * 8;
    const int lb = rg * TSa + c8 * 8;
    const int bo = (wave * 16 + n) * TSa + quad * 8;
    const int ao = n * TSa + quad * 8;

    f32x4 rvA[8], rvB[8], xvA[4], xvB[4];
    loadB_nt(rvA, rbase, 0);   loadA(xvA, xbase, 0);     // chunk 0 in flight

    {   // out = bias prologue: 262144 elems over 512 blocks = 2/thread
        int e = (blockIdx.x * 256 + tid) * 2;
        float2 bv;
        bv.x = bias[e & (OUT_F - 1)];
        bv.y = bias[(e + 1) & (OUT_F - 1)];
        *(float2*)(out + e) = bv;
    }
    loadB_nt(rvB, rbase, 128); loadA(xvB, xbase, 128);   // chunk 1 in flight

    f32x4 acc0 = {0.f, 0.f, 0.f, 0.f};
    f32x4 acc1 = {0.f, 0.f, 0.f, 0.f};

    // depth-2 schedule: cvt c (stalls only on c's loads, issued 2 chunks ago),
    // then issue c+2 into the reg bank just freed, barrier, MFMA c.
    // LDS[p] reuse is fenced by the c+1 barrier (mfma@c precedes it in program order).
    cvtB16(Bl[0], lb, rvA); cvtA16(Al[0], lb, xvA);
    loadB_nt(rvA, rbase, 256); loadA(xvA, xbase, 256);
    __syncthreads();
    mmstep(Bl[0], Al[0], bo, ao, acc0, acc1);

    cvtB16(Bl[1], lb, rvB); cvtA16(Al[1], lb, xvB);
    loadB_nt(rvB, rbase, 384); loadA(xvB, xbase, 384);
    __syncthreads();
    mmstep(Bl[1], Al[1], bo, ao, acc0, acc1);

    cvtB16(Bl[0], lb, rvA); cvtA16(Al[0], lb, xvA);
    __syncthreads();
    mmstep(Bl[0], Al[0], bo, ao, acc0, acc1);

    cvtB16(Bl[1], lb, rvB); cvtA16(Al[1], lb, xvB);
    __syncthreads();
    mmstep(Bl[1], Al[1], bo, ao, acc0, acc1);

    // C/D layout: col=lane&15 (n), row=quad*4+r (m)
    const int jcol = j0 + wave * 16 + n;
    #pragma unroll
    for (int r = 0; r < 4; ++r) {
        int br = quad * 4 + r;
        atomicAdd(&y_buf[br * IN_F + jcol], acc0[r]);
        atomicAdd(&y_buf[(br + 16) * IN_F + jcol], acc1[r]);
    }
}

// ---------------- K2: out += y @ codes^T (fused dequant) ----------------
// grid = 128 o-tiles * 4 k-splits = 512 blocks (2/CU), 8 chunks of 128 k
__global__ void __launch_bounds__(256, 3) k2_out(const int* __restrict__ idx,
                                                 const float* __restrict__ cb,
                                                 float* __restrict__ out) {
    __shared__ unsigned short Bl[2][64 * TSa];  // codes tile [64 o][128 k] bf16
    __shared__ unsigned short Al[2][32 * TSa];  // y tile     [32 b][128 k] bf16
    __shared__ unsigned int cbp[256];           // pair table: (i,j) -> bf16(cb[i]) | bf16(cb[j])<<16

    const int tid = threadIdx.x;
    const int ot = blockIdx.x & 127;
    const int kq = blockIdx.x >> 7;       // 0..3
    const int o0 = ot * 64;
    const int kb = kq * 1024;
    const int wave = tid >> 6, lane = tid & 63;
    const int n = lane & 15, quad = lane >> 4;
    const int rg = tid >> 4, c8 = tid & 15;

    const int*   ibase = idx + (size_t)(o0 + rg) * IN_F + kb + c8 * 8;
    const float* ybase = y_buf + (size_t)rg * IN_F + kb + c8 * 8;
    const int lb = rg * TSa + c8 * 8;
    const int bo = (wave * 16 + n) * TSa + quad * 8;
    const int ao = n * TSa + quad * 8;

    i32x4 ivA[8], ivB[8];
    f32x4 fvA[4], fvB[4];
    loadBi_nt(ivA, ibase, 0);   loadA(fvA, ybase, 0);    // chunk 0 in flight
    {   // dequant pair table (overlaps the loads)
        unsigned int lo = f2bf(cb[tid & 15]);
        unsigned int hi = f2bf(cb[tid >> 4]);
        cbp[tid] = lo | (hi << 16);
    }
    loadBi_nt(ivB, ibase, 128); loadA(fvB, ybase, 128);  // chunk 1 in flight
    __syncthreads();   // cbp visible; chunk 0/1 loads still in flight

    f32x4 acc0 = {0.f, 0.f, 0.f, 0.f};
    f32x4 acc1 = {0.f, 0.f, 0.f, 0.f};

    // 8 chunks, depth-2 pipeline (loads issued 2 chunks ahead)
    #define K2_STEP(P, IV, FV, DOLOAD, NOFF)                          \
        cvtC16(Bl[P], lb, IV, cbp); cvtA16(Al[P], lb, FV);            \
        if (DOLOAD) { loadBi_nt(IV, ibase, NOFF); loadA(FV, ybase, NOFF); } \
        __syncthreads();                                              \
        mmstep(Bl[P], Al[P], bo, ao, acc0, acc1);

    K2_STEP(0, ivA, fvA, 1, 256)
    K2_STEP(1, ivB, fvB, 1, 384)
    K2_STEP(0, ivA, fvA, 1, 512)
    K2_STEP(1, ivB, fvB, 1, 640)
    K2_STEP(0, ivA, fvA, 1, 768)
    K2_STEP(1, ivB, fvB, 1, 896)
    K2_STEP(0, ivA, fvA, 0, 0)
    K2_STEP(1, ivB, fvB, 0, 0)
    #undef K2_STEP

    const int ocol = o0 + wave * 16 + n;
    #pragma unroll
    for (int r = 0; r < 4; ++r) {
        int br = quad * 4 + r;
        atomicAdd(&out[(size_t)br * OUT_F + ocol], acc0[r]);
        atomicAdd(&out[(size_t)(br + 16) * OUT_F + ocol], acc1[r]);
    }
}

extern "C" void kernel_launch(void* const* d_in, const int* in_sizes, int n_in,
                              void* d_out, int out_size, void* d_ws, size_t ws_size,
                              hipStream_t stream) {
    (void)in_sizes; (void)n_in; (void)out_size; (void)d_ws; (void)ws_size;
    const float* x       = (const float*)d_in[0];
    const int*   indices = (const int*)d_in[1];
    const float* cb      = (const float*)d_in[2];
    const float* R       = (const float*)d_in[3];
    const float* bias    = (const float*)d_in[4];
    float* out  = (float*)d_out;

    k0_zero<<<dim3(128), dim3(256), 0, stream>>>();
    k1_xRT<<<dim3(512), dim3(256), 0, stream>>>(x, R, bias, out);
    k2_out<<<dim3(512), dim3(256), 0, stream>>>(indices, cb, out);
}